// Round 5
// baseline (105.360 us; speedup 1.0000x reference)
//
#include <hip/hip_runtime.h>
#include <math.h>

#define NN 320
#define DD 256
#define PS 328   // padded row stride (doubles) for prefix arrays, >= 321

// Packed weight rows: code(TABLE[cidx][v]) at bit 2*v; code: mapped 1->2,
// 2->1, 0->0; weight = code*0.5. v0 is 0 in every row.
__device__ __constant__ unsigned int c_PACK[7] =
    {0x2294u, 0x1554u, 0x1254u, 0x1554u, 0x1654u, 0x1154u, 0x2294u};

// Prep: blocks 0..19 transpose F(320x256) -> FT4 (float4-packed, [d4*NN+j]);
// block 20: meta[j] = {t, rlt, rle, pos|ev<<16} and zero acc[0..3].
__global__ __launch_bounds__(256) void prep_kernel(
    const float* __restrict__ F, const float* __restrict__ yt,
    const int* __restrict__ ye, float4* __restrict__ FT4,
    float4* __restrict__ meta, float* __restrict__ acc) {
    __shared__ float sh[64 * 65];
    const int b = blockIdx.x;
    if (b < 20) {
        float (*tile)[65] = (float(*)[65])sh;
        const int I = b % 5;            // i-tile 0..4
        const int J = b / 5;            // d-tile 0..3
        const int lane = threadIdx.x & 63;
        const int quad = threadIdx.x >> 6;
#pragma unroll
        for (int r0 = 0; r0 < 64; r0 += 4) {
            const int r = r0 + quad;
            tile[r][lane] = F[(I * 64 + r) * DD + J * 64 + lane];
        }
        __syncthreads();
#pragma unroll
        for (int q = 0; q < 16; q += 4) {
            const int d4 = q + quad;
            float4 v = make_float4(tile[lane][d4 * 4 + 0], tile[lane][d4 * 4 + 1],
                                   tile[lane][d4 * 4 + 2], tile[lane][d4 * 4 + 3]);
            FT4[(J * 16 + d4) * NN + I * 64 + lane] = v;
        }
    } else {
        if (threadIdx.x < 4) acc[threadIdx.x] = 0.0f;   // loss, has, ticket, pad
        float* s_t = sh;
        for (int j = threadIdx.x; j < NN; j += 256) s_t[j] = yt[j];
        __syncthreads();
        for (int j = threadIdx.x; j < NN; j += 256) {
            const float tj = s_t[j];
            int lt = 0, le = 0, pos = 0;
            for (int l = 0; l < NN; ++l) {
                const float tl = s_t[l];
                lt  += (tl < tj);
                le  += (tl <= tj);
                pos += (tl < tj) || (tl == tj && l < j);   // tie-break by index
            }
            meta[j] = make_float4(tj, __int_as_float(lt), __int_as_float(le),
                                  __int_as_float(pos | (ye[j] << 16)));
        }
    }
}

// Pair+scan: block i computes row i of L and f64 per-class exclusive prefix
// sums of E[i][.] (diagonal excluded) in sorted-t order. Shuffle-based scan:
// 3 barriers total.
__global__ __launch_bounds__(NN) void pair_scan_kernel(
    const float* __restrict__ F, const float4* __restrict__ FT4,
    const float4* __restrict__ meta, float* __restrict__ L,
    double* __restrict__ P0, double* __restrict__ P1) {
    __shared__ __align__(16) float fi[DD];
    __shared__ double sA0[NN];
    __shared__ double sA1[NN];
    __shared__ double sW0[5];
    __shared__ double sW1[5];
    const int i = blockIdx.x;
    const int j = threadIdx.x;
    const int wave = j >> 6, lane = j & 63;
    if (j < DD) fi[j] = F[i * DD + j];
    __syncthreads();

    const float4* __restrict__ fi4 = (const float4*)fi;
    float a0 = 0.f, a1 = 0.f, a2 = 0.f, a3 = 0.f;
#pragma unroll 8
    for (int d4 = 0; d4 < DD / 4; ++d4) {
        const float4 f4 = fi4[d4];
        const float4 g4 = FT4[d4 * NN + j];
        const float u0 = f4.x - g4.x, u1 = f4.y - g4.y;
        const float u2 = f4.z - g4.z, u3 = f4.w - g4.w;
        a0 = fmaf(u0, u0, a0);
        a1 = fmaf(u1, u1, a1);
        a2 = fmaf(u2, u2, a2);
        a3 = fmaf(u3, u3, a3);
    }
    const float d2 = (a0 + a1) + (a2 + a3);
    const float nrm = (d2 > 0.f) ? sqrtf(d2) : 0.f;
    const float lg = -0.5f * nrm;                 // -norm/TEMP, TEMP=2
    L[i * NN + j] = lg;                           // symmetric
    const float e = expf(lg);

    // scatter into sorted-t order, split by event class; diagonal EXCLUDED
    const int pw  = __float_as_int(meta[j].w);
    const int pos = pw & 0xFFFF;
    const int ev  = pw >> 16;
    const double ed = (j == i) ? 0.0 : (double)e;
    sA0[pos] = ev ? 0.0 : ed;
    sA1[pos] = ev ? ed : 0.0;
    __syncthreads();

    // wave-local inclusive scan over sorted index j
    const double v0 = sA0[j], v1 = sA1[j];
    double inc0 = v0, inc1 = v1;
#pragma unroll
    for (int off = 1; off < 64; off <<= 1) {
        const double u0 = __shfl_up(inc0, off);
        const double u1 = __shfl_up(inc1, off);
        if (lane >= off) { inc0 += u0; inc1 += u1; }
    }
    if (lane == 63) { sW0[wave] = inc0; sW1[wave] = inc1; }
    __syncthreads();
    double o0 = 0.0, o1 = 0.0;
    for (int w = 0; w < wave; ++w) { o0 += sW0[w]; o1 += sW1[w]; }

    P0[i * PS + j] = inc0 + o0 - v0;   // exclusive
    P1[i * PS + j] = inc1 + o1 - v1;
    if (j == NN - 1) {
        P0[i * PS + NN] = inc0 + o0;   // totals
        P1[i * PS + NN] = inc1 + o1;
    }
}

// Anchor+finalize: block k, thread i; denominator from 6 f64 rank-range sums.
// Per-block (loss_k, has_k) atomicAdd'ed; last block (ticket) divides.
__global__ __launch_bounds__(NN) void anchor_final_kernel(
    const float4* __restrict__ meta, const float* __restrict__ L,
    const double* __restrict__ P0, const double* __restrict__ P1,
    float* __restrict__ acc, float* __restrict__ out) {
    __shared__ float swl[5];
    __shared__ float swn[5];
    const int k = blockIdx.x;
    const int i = threadIdx.x;
    const int wave = i >> 6, lane = i & 63;

    const float4 mk = meta[k];   // uniform
    const float4 mi = meta[i];   // coalesced
    const float tk = mk.x, ti = mi.x;
    const int rlt_k = __float_as_int(mk.y), rle_k = __float_as_int(mk.z);
    const int evk   = __float_as_int(mk.w) >> 16;
    const int rlt_i = __float_as_int(mi.y), rle_i = __float_as_int(mi.z);
    const int evi   = __float_as_int(mi.w) >> 16;

    const int sgn = (ti > tk) ? 1 : ((ti < tk) ? -1 : 0);
    const unsigned pack = c_PACK[3 + sgn * (evi + 2 * evk)];
    const int rlo = min(rlt_i, rlt_k);   // rank_lt(min(ti,tk))
    const int rhi = max(rle_i, rle_k);   // rank_le(max(ti,tk))

    const double* __restrict__ b0 = P0 + i * PS;
    const double* __restrict__ b1 = P1 + i * PS;
    const double q0lo = b0[rlo], q0hi = b0[rhi], q0a = b0[rlt_k], q0b = b0[rle_k], t0 = b0[NN];
    const double q1lo = b1[rlo], q1hi = b1[rhi], q1a = b1[rlt_k], q1b = b1[rle_k], t1 = b1[NN];

    const double LO0 = q0lo, HI0 = t0 - q0hi, MI0 = q0hi - q0lo - (q0b - q0a);
    const double LO1 = q1lo, HI1 = t1 - q1hi, MI1 = q1hi - q1lo - (q1b - q1a);

    const double c1 = (double)((pack >> 2) & 3u),  c2 = (double)((pack >> 4) & 3u);
    const double c3 = (double)((pack >> 6) & 3u),  c4 = (double)((pack >> 8) & 3u);
    const double c5 = (double)((pack >> 10) & 3u), c6 = (double)((pack >> 12) & 3u);

    const double dx = c1 * LO0 + c2 * MI0 + c3 * HI0
                    + c4 * LO1 + c5 * MI1 + c6 * HI1;   // 2*denom, diag-free

    float lp = 0.f, np = 0.f;
    if (i != k && dx > 0.0) {
        lp = L[k * NN + i] - logf((float)(0.5 * dx));   // L[i][k]==L[k][i]
        np = 1.f;
    }
#pragma unroll
    for (int off = 32; off > 0; off >>= 1) {
        lp += __shfl_down(lp, off);
        np += __shfl_down(np, off);
    }
    if (lane == 0) { swl[wave] = lp; swn[wave] = np; }
    __syncthreads();
    if (i == 0) {
        float s = 0.f, n = 0.f;
#pragma unroll
        for (int w = 0; w < 5; ++w) { s += swl[w]; n += swn[w]; }
        if (n > 0.f) {
            atomicAdd(&acc[0], -(s / n));   // Σ loss_k
            atomicAdd(&acc[1], 1.0f);       // Σ has_pos
        }
        __threadfence();
        const unsigned tkt = atomicAdd((unsigned int*)(acc + 2), 1u);
        if (tkt == NN - 1) {
            const float ls = atomicAdd(&acc[0], 0.0f);  // coherent reads
            const float hs = atomicAdd(&acc[1], 0.0f);
            out[0] = ls / hs;
        }
    }
}

extern "C" void kernel_launch(void* const* d_in, const int* in_sizes, int n_in,
                              void* d_out, int out_size, void* d_ws, size_t ws_size,
                              hipStream_t stream) {
    const float* F  = (const float*)d_in[0];   // features (320,256) f32
    const float* yt = (const float*)d_in[1];   // y_times (320,) f32
    const int*   ye = (const int*)d_in[2];     // y_events (320,) i32
    float* out = (float*)d_out;
    float* ws  = (float*)d_ws;

    float4* meta = (float4*)ws;                        // 320 float4
    float4* FT4  = (float4*)(ws + 4 * NN);             // 64*320 float4
    float*  L    = ws + 4 * NN + 4 * (DD / 4) * NN;    // 320*320 f32
    float*  acc  = L + NN * NN;                        // 4 f32 (8B-aligned end)
    double* P0   = (double*)(acc + 4);                 // 320*PS f64
    double* P1   = P0 + NN * PS;                       // 320*PS f64

    prep_kernel<<<21, 256, 0, stream>>>(F, yt, ye, FT4, meta, acc);
    pair_scan_kernel<<<NN, NN, 0, stream>>>(F, FT4, meta, L, P0, P1);
    anchor_final_kernel<<<NN, NN, 0, stream>>>(meta, L, P0, P1, acc, out);
}

// Round 6
// 104.964 us; speedup vs baseline: 1.0038x; 1.0038x over previous
//
#include <hip/hip_runtime.h>
#include <math.h>

#define NN 320
#define DD 256
#define PSF 328   // padded f32 row stride for prefix arrays, >= 321

// Packed weight rows: code(TABLE[cidx][v]) at bit 2*v; code: mapped 1->2,
// 2->1, 0->0; weight = code*0.5. v0 is 0 in every row.
__device__ __constant__ unsigned int c_PACK[7] =
    {0x2294u, 0x1554u, 0x1254u, 0x1554u, 0x1654u, 0x1154u, 0x2294u};

// Prep: blocks 0..19 transpose F(320x256) -> FT4 (float4-packed, [d4*NN+j]);
// block 20: meta[j] = {t, rlt, rle, pos|ev<<16}, zero acc[0..3].
__global__ __launch_bounds__(256) void prep_kernel(
    const float* __restrict__ F, const float* __restrict__ yt,
    const int* __restrict__ ye, float4* __restrict__ FT4,
    float4* __restrict__ meta, float* __restrict__ acc) {
    __shared__ float sh[64 * 65];
    const int b = blockIdx.x;
    if (b < 20) {
        float (*tile)[65] = (float(*)[65])sh;
        const int I = b % 5;            // i-tile 0..4
        const int J = b / 5;            // d-tile 0..3
        const int lane = threadIdx.x & 63;
        const int quad = threadIdx.x >> 6;
#pragma unroll
        for (int r0 = 0; r0 < 64; r0 += 4) {
            const int r = r0 + quad;
            tile[r][lane] = F[(I * 64 + r) * DD + J * 64 + lane];
        }
        __syncthreads();
#pragma unroll
        for (int q = 0; q < 16; q += 4) {
            const int d4 = q + quad;
            float4 v = make_float4(tile[lane][d4 * 4 + 0], tile[lane][d4 * 4 + 1],
                                   tile[lane][d4 * 4 + 2], tile[lane][d4 * 4 + 3]);
            FT4[(J * 16 + d4) * NN + I * 64 + lane] = v;
        }
    } else {
        if (threadIdx.x < 4) acc[threadIdx.x] = 0.0f;   // loss, has, ticket, pad
        float* s_t = sh;
        for (int j = threadIdx.x; j < NN; j += 256) s_t[j] = yt[j];
        __syncthreads();
        for (int j = threadIdx.x; j < NN; j += 256) {
            const float tj = s_t[j];
            int lt = 0, le = 0, pos = 0;
            for (int l = 0; l < NN; ++l) {
                const float tl = s_t[l];
                lt  += (tl < tj);
                le  += (tl <= tj);
                pos += (tl < tj) || (tl == tj && l < j);   // tie-break by index
            }
            meta[j] = make_float4(tj, __int_as_float(lt), __int_as_float(le),
                                  __int_as_float(pos | (ye[j] << 16)));
        }
    }
}

// Pair+scan: block i computes row i of L and per-class exclusive prefix sums
// of E[i][.] (diagonal EXCLUDED) in sorted-t order. f64 shuffle scan, f32 store.
__global__ __launch_bounds__(NN) void pair_scan_kernel(
    const float* __restrict__ F, const float4* __restrict__ FT4,
    const float4* __restrict__ meta, float* __restrict__ L,
    float* __restrict__ P0, float* __restrict__ P1) {
    __shared__ __align__(16) float fi[DD];
    __shared__ double sA0[NN];
    __shared__ double sA1[NN];
    __shared__ double sW0[5];
    __shared__ double sW1[5];
    const int i = blockIdx.x;
    const int j = threadIdx.x;
    const int wave = j >> 6, lane = j & 63;
    if (j < DD) fi[j] = F[i * DD + j];
    __syncthreads();

    const float4* __restrict__ fi4 = (const float4*)fi;
    float a0 = 0.f, a1 = 0.f, a2 = 0.f, a3 = 0.f;
#pragma unroll 8
    for (int d4 = 0; d4 < DD / 4; ++d4) {
        const float4 f4 = fi4[d4];
        const float4 g4 = FT4[d4 * NN + j];
        const float u0 = f4.x - g4.x, u1 = f4.y - g4.y;
        const float u2 = f4.z - g4.z, u3 = f4.w - g4.w;
        a0 = fmaf(u0, u0, a0);
        a1 = fmaf(u1, u1, a1);
        a2 = fmaf(u2, u2, a2);
        a3 = fmaf(u3, u3, a3);
    }
    const float d2 = (a0 + a1) + (a2 + a3);
    const float nrm = (d2 > 0.f) ? sqrtf(d2) : 0.f;
    const float lg = -0.5f * nrm;                 // -norm/TEMP, TEMP=2
    L[i * NN + j] = lg;                           // symmetric, bit-exact
    const float e = expf(lg);

    // scatter into sorted-t order, split by event class; diagonal EXCLUDED
    const int pw  = __float_as_int(meta[j].w);
    const int pos = pw & 0xFFFF;
    const int ev  = pw >> 16;
    const double ed = (j == i) ? 0.0 : (double)e;
    sA0[pos] = ev ? 0.0 : ed;
    sA1[pos] = ev ? ed : 0.0;
    __syncthreads();

    // wave-local inclusive scan over sorted index j, then wave-offset fixup
    const double v0 = sA0[j], v1 = sA1[j];
    double inc0 = v0, inc1 = v1;
#pragma unroll
    for (int off = 1; off < 64; off <<= 1) {
        const double u0 = __shfl_up(inc0, off);
        const double u1 = __shfl_up(inc1, off);
        if (lane >= off) { inc0 += u0; inc1 += u1; }
    }
    if (lane == 63) { sW0[wave] = inc0; sW1[wave] = inc1; }
    __syncthreads();
    double o0 = 0.0, o1 = 0.0;
    for (int w = 0; w < wave; ++w) { o0 += sW0[w]; o1 += sW1[w]; }

    P0[i * PSF + j] = (float)(inc0 + o0 - v0);   // exclusive
    P1[i * PSF + j] = (float)(inc1 + o1 - v1);
    if (j == NN - 1) {
        P0[i * PSF + NN] = (float)(inc0 + o0);   // totals
        P1[i * PSF + NN] = (float)(inc1 + o1);
    }
}

// Anchor+finalize: block k, thread i. Exact reference classification via two
// binary searches on sorted t (mirror thresholds tk ± |ti-tk|, f32 compares
// identical to the reference's). Denominator from rank-range sums.
__global__ __launch_bounds__(NN) void anchor_final_kernel(
    const float4* __restrict__ meta, const float* __restrict__ L,
    const float* __restrict__ P0, const float* __restrict__ P1,
    float* __restrict__ acc, float* __restrict__ out) {
    __shared__ float s_ts[NN];    // t values in sorted order
    __shared__ float swl[5];
    __shared__ float swn[5];
    const int k = blockIdx.x;
    const int i = threadIdx.x;
    const int wave = i >> 6, lane = i & 63;

    const float4 mi = meta[i];    // coalesced
    const int pwi = __float_as_int(mi.w);
    s_ts[pwi & 0xFFFF] = mi.x;    // scatter into sorted order
    __syncthreads();

    const float4 mk = meta[k];    // uniform
    const float tk = mk.x, ti = mi.x;
    const int rlt_k = __float_as_int(mk.y), rle_k = __float_as_int(mk.z);
    const int evk   = __float_as_int(mk.w) >> 16;
    const int evi   = pwi >> 16;

    const float absi = fabsf(ti - tk);
    const int sgn = (ti > tk) ? 1 : ((ti < tk) ? -1 : 0);
    const unsigned pack = c_PACK[3 + sgn * (evi + 2 * evk)];

    // r_lo = first r with (ts[r]-tk) >= -absi  (td=1 region is [0, r_lo))
    int lo = 0, hi = NN;
    while (lo < hi) {
        const int mid = (lo + hi) >> 1;
        if (s_ts[mid] - tk >= -absi) hi = mid; else lo = mid + 1;
    }
    const int r_lo = lo;
    // r_hi = first r with (ts[r]-tk) > absi   (td=3 region is [r_hi, NN))
    lo = 0; hi = NN;
    while (lo < hi) {
        const int mid = (lo + hi) >> 1;
        if (s_ts[mid] - tk > absi) hi = mid; else lo = mid + 1;
    }
    const int r_hi = lo;

    const float* __restrict__ b0 = P0 + i * PSF;
    const float* __restrict__ b1 = P1 + i * PSF;
    const float p0lo = b0[r_lo], p0hi = b0[r_hi], p0a = b0[rlt_k], p0b = b0[rle_k], t0 = b0[NN];
    const float p1lo = b1[r_lo], p1hi = b1[r_hi], p1a = b1[rlt_k], p1b = b1[rle_k], t1 = b1[NN];

    // LO=td1, HI=td3, MID=td2 (mid range minus EQ ties; diag already excluded)
    const float LO0 = p0lo, HI0 = t0 - p0hi, MI0 = p0hi - p0lo - (p0b - p0a);
    const float LO1 = p1lo, HI1 = t1 - p1hi, MI1 = p1hi - p1lo - (p1b - p1a);

    const float c1 = (float)((pack >> 2) & 3u),  c2 = (float)((pack >> 4) & 3u);
    const float c3 = (float)((pack >> 6) & 3u),  c4 = (float)((pack >> 8) & 3u);
    const float c5 = (float)((pack >> 10) & 3u), c6 = (float)((pack >> 12) & 3u);

    const float dx = c1 * LO0 + c2 * MI0 + c3 * HI0
                   + c4 * LO1 + c5 * MI1 + c6 * HI1;   // 2*denom

    float lp = 0.f, np = 0.f;
    if (i != k && dx > 0.f) {
        lp = L[k * NN + i] - logf(0.5f * dx);   // L[i][k]==L[k][i]
        np = 1.f;
    }
#pragma unroll
    for (int off = 32; off > 0; off >>= 1) {
        lp += __shfl_down(lp, off);
        np += __shfl_down(np, off);
    }
    if (lane == 0) { swl[wave] = lp; swn[wave] = np; }
    __syncthreads();
    if (i == 0) {
        float s = 0.f, n = 0.f;
#pragma unroll
        for (int w = 0; w < 5; ++w) { s += swl[w]; n += swn[w]; }
        if (n > 0.f) {
            atomicAdd(&acc[0], -(s / n));   // Σ loss_k
            atomicAdd(&acc[1], 1.0f);       // Σ has_pos
        }
        __threadfence();
        const unsigned tkt = atomicAdd((unsigned int*)(acc + 2), 1u);
        if (tkt == NN - 1) {
            const float ls = atomicAdd(&acc[0], 0.0f);  // coherent reads
            const float hs = atomicAdd(&acc[1], 0.0f);
            out[0] = ls / hs;
        }
    }
}

extern "C" void kernel_launch(void* const* d_in, const int* in_sizes, int n_in,
                              void* d_out, int out_size, void* d_ws, size_t ws_size,
                              hipStream_t stream) {
    const float* F  = (const float*)d_in[0];   // features (320,256) f32
    const float* yt = (const float*)d_in[1];   // y_times (320,) f32
    const int*   ye = (const int*)d_in[2];     // y_events (320,) i32
    float* out = (float*)d_out;
    float* ws  = (float*)d_ws;

    float4* meta = (float4*)ws;                        // 320 float4
    float4* FT4  = (float4*)(ws + 4 * NN);             // 64*320 float4
    float*  L    = ws + 4 * NN + 4 * (DD / 4) * NN;    // 320*320 f32
    float*  acc  = L + NN * NN;                        // 4 f32
    float*  P0   = acc + 4;                            // 320*PSF f32
    float*  P1   = P0 + NN * PSF;                      // 320*PSF f32

    prep_kernel<<<21, 256, 0, stream>>>(F, yt, ye, FT4, meta, acc);
    pair_scan_kernel<<<NN, NN, 0, stream>>>(F, FT4, meta, L, P0, P1);
    anchor_final_kernel<<<NN, NN, 0, stream>>>(meta, L, P0, P1, acc, out);
}

// Round 7
// 96.461 us; speedup vs baseline: 1.0923x; 1.0882x over previous
//
#include <hip/hip_runtime.h>
#include <math.h>

#define NN 320
#define DD 256
#define PSF 328   // padded f32 row stride for prefix arrays, >= 321

// Packed weight rows: code(TABLE[cidx][v]) at bit 2*v; code: mapped 1->2,
// 2->1, 0->0; weight = code*0.5. v0 is 0 in every row.
__device__ __constant__ unsigned int c_PACK[7] =
    {0x2294u, 0x1554u, 0x1254u, 0x1554u, 0x1654u, 0x1154u, 0x2294u};

// Prep: blocks 0..19 transpose F(320x256) -> FT4 (float4-packed, [d4*NN+j]);
// block 20: meta[j] = {t, rlt, rle, pos|ev<<16}.
__global__ __launch_bounds__(256) void prep_kernel(
    const float* __restrict__ F, const float* __restrict__ yt,
    const int* __restrict__ ye, float4* __restrict__ FT4,
    float4* __restrict__ meta) {
    __shared__ float sh[64 * 65];
    const int b = blockIdx.x;
    if (b < 20) {
        float (*tile)[65] = (float(*)[65])sh;
        const int I = b % 5;            // i-tile 0..4
        const int J = b / 5;            // d-tile 0..3
        const int lane = threadIdx.x & 63;
        const int quad = threadIdx.x >> 6;
#pragma unroll
        for (int r0 = 0; r0 < 64; r0 += 4) {
            const int r = r0 + quad;
            tile[r][lane] = F[(I * 64 + r) * DD + J * 64 + lane];
        }
        __syncthreads();
#pragma unroll
        for (int q = 0; q < 16; q += 4) {
            const int d4 = q + quad;
            float4 v = make_float4(tile[lane][d4 * 4 + 0], tile[lane][d4 * 4 + 1],
                                   tile[lane][d4 * 4 + 2], tile[lane][d4 * 4 + 3]);
            FT4[(J * 16 + d4) * NN + I * 64 + lane] = v;
        }
    } else {
        float* s_t = sh;
        for (int j = threadIdx.x; j < NN; j += 256) s_t[j] = yt[j];
        __syncthreads();
        for (int j = threadIdx.x; j < NN; j += 256) {
            const float tj = s_t[j];
            int lt = 0, le = 0, pos = 0;
            for (int l = 0; l < NN; ++l) {
                const float tl = s_t[l];
                lt  += (tl < tj);
                le  += (tl <= tj);
                pos += (tl < tj) || (tl == tj && l < j);   // tie-break by index
            }
            meta[j] = make_float4(tj, __int_as_float(lt), __int_as_float(le),
                                  __int_as_float(pos | (ye[j] << 16)));
        }
    }
}

// Pair+scan: block i computes row i of L and per-class exclusive prefix sums
// of E[i][.] (diagonal EXCLUDED) in sorted-t order. f64 shuffle scan, f32 store.
__global__ __launch_bounds__(NN) void pair_scan_kernel(
    const float* __restrict__ F, const float4* __restrict__ FT4,
    const float4* __restrict__ meta, float* __restrict__ L,
    float* __restrict__ P0, float* __restrict__ P1) {
    __shared__ __align__(16) float fi[DD];
    __shared__ double sA0[NN];
    __shared__ double sA1[NN];
    __shared__ double sW0[5];
    __shared__ double sW1[5];
    const int i = blockIdx.x;
    const int j = threadIdx.x;
    const int wave = j >> 6, lane = j & 63;
    if (j < DD) fi[j] = F[i * DD + j];
    __syncthreads();

    const float4* __restrict__ fi4 = (const float4*)fi;
    float a0 = 0.f, a1 = 0.f, a2 = 0.f, a3 = 0.f;
#pragma unroll 8
    for (int d4 = 0; d4 < DD / 4; ++d4) {
        const float4 f4 = fi4[d4];
        const float4 g4 = FT4[d4 * NN + j];
        const float u0 = f4.x - g4.x, u1 = f4.y - g4.y;
        const float u2 = f4.z - g4.z, u3 = f4.w - g4.w;
        a0 = fmaf(u0, u0, a0);
        a1 = fmaf(u1, u1, a1);
        a2 = fmaf(u2, u2, a2);
        a3 = fmaf(u3, u3, a3);
    }
    const float d2 = (a0 + a1) + (a2 + a3);
    const float nrm = (d2 > 0.f) ? sqrtf(d2) : 0.f;
    const float lg = -0.5f * nrm;                 // -norm/TEMP, TEMP=2
    L[i * NN + j] = lg;                           // symmetric, bit-exact
    const float e = expf(lg);

    // scatter into sorted-t order, split by event class; diagonal EXCLUDED
    const int pw  = __float_as_int(meta[j].w);
    const int pos = pw & 0xFFFF;
    const int ev  = pw >> 16;
    const double ed = (j == i) ? 0.0 : (double)e;
    sA0[pos] = ev ? 0.0 : ed;
    sA1[pos] = ev ? ed : 0.0;
    __syncthreads();

    // wave-local inclusive scan over sorted index j, then wave-offset fixup
    const double v0 = sA0[j], v1 = sA1[j];
    double inc0 = v0, inc1 = v1;
#pragma unroll
    for (int off = 1; off < 64; off <<= 1) {
        const double u0 = __shfl_up(inc0, off);
        const double u1 = __shfl_up(inc1, off);
        if (lane >= off) { inc0 += u0; inc1 += u1; }
    }
    if (lane == 63) { sW0[wave] = inc0; sW1[wave] = inc1; }
    __syncthreads();
    double o0 = 0.0, o1 = 0.0;
    for (int w = 0; w < wave; ++w) { o0 += sW0[w]; o1 += sW1[w]; }

    P0[i * PSF + j] = (float)(inc0 + o0 - v0);   // exclusive
    P1[i * PSF + j] = (float)(inc1 + o1 - v1);
    if (j == NN - 1) {
        P0[i * PSF + NN] = (float)(inc0 + o0);   // totals
        P1[i * PSF + NN] = (float)(inc1 + o1);
    }
}

// Anchor: block k, thread i. Exact reference classification via two binary
// searches on sorted t (mirror thresholds tk +- |ti-tk|, f32 compares
// identical to the reference's). Denominator from rank-range sums.
// NO atomics: per-k partials written to accv[k] / accv[NN+k].
__global__ __launch_bounds__(NN) void anchor_kernel(
    const float4* __restrict__ meta, const float* __restrict__ L,
    const float* __restrict__ P0, const float* __restrict__ P1,
    float* __restrict__ accv) {
    __shared__ float s_ts[NN];    // t values in sorted order
    __shared__ float swl[5];
    __shared__ float swn[5];
    const int k = blockIdx.x;
    const int i = threadIdx.x;
    const int wave = i >> 6, lane = i & 63;

    const float4 mi = meta[i];    // coalesced
    const int pwi = __float_as_int(mi.w);
    s_ts[pwi & 0xFFFF] = mi.x;    // scatter into sorted order
    __syncthreads();

    const float4 mk = meta[k];    // uniform
    const float tk = mk.x, ti = mi.x;
    const int rlt_k = __float_as_int(mk.y), rle_k = __float_as_int(mk.z);
    const int evk   = __float_as_int(mk.w) >> 16;
    const int evi   = pwi >> 16;

    const float absi = fabsf(ti - tk);
    const int sgn = (ti > tk) ? 1 : ((ti < tk) ? -1 : 0);
    const unsigned pack = c_PACK[3 + sgn * (evi + 2 * evk)];

    // r_lo = first r with (ts[r]-tk) >= -absi  (td=1 region is [0, r_lo))
    int lo = 0, hi = NN;
    while (lo < hi) {
        const int mid = (lo + hi) >> 1;
        if (s_ts[mid] - tk >= -absi) hi = mid; else lo = mid + 1;
    }
    const int r_lo = lo;
    // r_hi = first r with (ts[r]-tk) > absi   (td=3 region is [r_hi, NN))
    lo = 0; hi = NN;
    while (lo < hi) {
        const int mid = (lo + hi) >> 1;
        if (s_ts[mid] - tk > absi) hi = mid; else lo = mid + 1;
    }
    const int r_hi = lo;

    const float* __restrict__ b0 = P0 + i * PSF;
    const float* __restrict__ b1 = P1 + i * PSF;
    const float p0lo = b0[r_lo], p0hi = b0[r_hi], p0a = b0[rlt_k], p0b = b0[rle_k], t0 = b0[NN];
    const float p1lo = b1[r_lo], p1hi = b1[r_hi], p1a = b1[rlt_k], p1b = b1[rle_k], t1 = b1[NN];

    // LO=td1, HI=td3, MID=td2 (mid range minus EQ ties; diag already excluded)
    const float LO0 = p0lo, HI0 = t0 - p0hi, MI0 = p0hi - p0lo - (p0b - p0a);
    const float LO1 = p1lo, HI1 = t1 - p1hi, MI1 = p1hi - p1lo - (p1b - p1a);

    const float c1 = (float)((pack >> 2) & 3u),  c2 = (float)((pack >> 4) & 3u);
    const float c3 = (float)((pack >> 6) & 3u),  c4 = (float)((pack >> 8) & 3u);
    const float c5 = (float)((pack >> 10) & 3u), c6 = (float)((pack >> 12) & 3u);

    const float dx = c1 * LO0 + c2 * MI0 + c3 * HI0
                   + c4 * LO1 + c5 * MI1 + c6 * HI1;   // 2*denom

    float lp = 0.f, np = 0.f;
    if (i != k && dx > 0.f) {
        lp = L[k * NN + i] - logf(0.5f * dx);   // L[i][k]==L[k][i]
        np = 1.f;
    }
#pragma unroll
    for (int off = 32; off > 0; off >>= 1) {
        lp += __shfl_down(lp, off);
        np += __shfl_down(np, off);
    }
    if (lane == 0) { swl[wave] = lp; swn[wave] = np; }
    __syncthreads();
    if (i == 0) {
        float s = 0.f, n = 0.f;
#pragma unroll
        for (int w = 0; w < 5; ++w) { s += swl[w]; n += swn[w]; }
        accv[k]      = s;   // Σ_i logp(i,k)
        accv[NN + k] = n;   // Np(k)
    }
}

// Finalize: per-anchor loss, reduce 320 anchors to the scalar.
__global__ __launch_bounds__(NN) void finalize_kernel(
    const float* __restrict__ accv, float* __restrict__ out) {
    __shared__ float s_l[5];
    __shared__ float s_h[5];
    const int k = threadIdx.x;
    const int wave = k >> 6, lane = k & 63;
    const float np = accv[NN + k];
    float loss = (np > 0.f) ? (-accv[k] / np) : 0.f;
    float has  = (np > 0.f) ? 1.f : 0.f;
#pragma unroll
    for (int off = 32; off > 0; off >>= 1) {
        loss += __shfl_down(loss, off);
        has  += __shfl_down(has, off);
    }
    if (lane == 0) { s_l[wave] = loss; s_h[wave] = has; }
    __syncthreads();
    if (k == 0) {
        float tl = 0.f, th = 0.f;
#pragma unroll
        for (int w = 0; w < 5; ++w) { tl += s_l[w]; th += s_h[w]; }
        out[0] = tl / th;
    }
}

extern "C" void kernel_launch(void* const* d_in, const int* in_sizes, int n_in,
                              void* d_out, int out_size, void* d_ws, size_t ws_size,
                              hipStream_t stream) {
    const float* F  = (const float*)d_in[0];   // features (320,256) f32
    const float* yt = (const float*)d_in[1];   // y_times (320,) f32
    const int*   ye = (const int*)d_in[2];     // y_events (320,) i32
    float* out = (float*)d_out;
    float* ws  = (float*)d_ws;

    float4* meta = (float4*)ws;                        // 320 float4
    float4* FT4  = (float4*)(ws + 4 * NN);             // 64*320 float4
    float*  L    = ws + 4 * NN + 4 * (DD / 4) * NN;    // 320*320 f32
    float*  P0   = L + NN * NN;                        // 320*PSF f32
    float*  P1   = P0 + NN * PSF;                      // 320*PSF f32
    float*  accv = P1 + NN * PSF;                      // 2*320 f32

    prep_kernel<<<21, 256, 0, stream>>>(F, yt, ye, FT4, meta);
    pair_scan_kernel<<<NN, NN, 0, stream>>>(F, FT4, meta, L, P0, P1);
    anchor_kernel<<<NN, NN, 0, stream>>>(meta, L, P0, P1, accv);
    finalize_kernel<<<1, NN, 0, stream>>>(accv, out);
}